// Round 9
// baseline (10127.853 us; speedup 1.0000x reference)
//
#include <hip/hip_runtime.h>
#include <hip/hip_bf16.h>
#include <stdint.h>

// Problem constants (fixed by the reference): T=512, B=64, IN=H=1024, L=2
#define TT 512
#define BB 64
#define HH 1024
#define BH 65536    // B*H elements
#define KD 2048     // IN+H == H+H

typedef __attribute__((ext_vector_type(8))) short short8;
typedef __attribute__((ext_vector_type(4))) float f32x4;

__device__ __forceinline__ unsigned short f2bf(float f) {
  union { float f; unsigned int u; } v; v.f = f;
  unsigned int r = v.u + 0x7fffu + ((v.u >> 16) & 1u);  // RNE
  return (unsigned short)(r >> 16);
}
__device__ __forceinline__ float fsig(float x)  { return 1.0f / (1.0f + __expf(-x)); }
__device__ __forceinline__ float ftanhf(float x){ return 1.0f - 2.0f / (__expf(2.0f * x) + 1.0f); }

// ---------------- x -> bf16 ----------------
__global__ void cvt_x_kernel(const float* __restrict__ x, unsigned short* __restrict__ xbf) {
  const int n4 = (TT * BB * 1024) / 4;
  int stride = gridDim.x * blockDim.x;
  for (int i = blockIdx.x * blockDim.x + threadIdx.x; i < n4; i += stride) {
    float4 v = ((const float4*)x)[i];
    unsigned long long p = (unsigned long long)f2bf(v.x)
        | ((unsigned long long)f2bf(v.y) << 16)
        | ((unsigned long long)f2bf(v.z) << 32)
        | ((unsigned long long)f2bf(v.w) << 48);
    ((unsigned long long*)xbf)[i] = p;
  }
}

// ---------------- W [4096][2048] f32 -> bf16, LDS-image layout ----------------
// Ws[g][kk 0..63][nrow 0..31][hi 0..3][8 bf16]  (16B chunks; 128 KB per slice g)
// nrow: nt=nrow>>4, q=(nrow>>2)&3, jl=nrow&3 -> W row = q*1024 + g*8 + nt*4 + jl
// kk<32: k = kk*32 + hi*8 (x-half); kk>=32: k = 1024 + (kk-32)*32 + hi*8 (h-half)
__global__ void cvt_w_kernel(const float* __restrict__ W, unsigned short* __restrict__ Ws) {
  int idx = blockIdx.x * blockDim.x + threadIdx.x;   // < 128*64*32*4 = 1,048,576
  int hi = idx & 3;
  int nr = (idx >> 2) & 31;
  int kk = (idx >> 7) & 63;
  int g  = idx >> 13;
  int q  = (nr >> 2) & 3;
  int nt = nr >> 4;
  int jl = nr & 3;
  int grow = (q << 10) + (g << 3) + (nt << 2) + jl;
  int k = ((kk < 32) ? (kk << 5) : (1024 + ((kk - 32) << 5))) + (hi << 3);
  const float* src = W + (size_t)grow * KD + k;
  float4 v0 = ((const float4*)src)[0];
  float4 v1 = ((const float4*)src)[1];
  unsigned long long p0 = (unsigned long long)f2bf(v0.x)
      | ((unsigned long long)f2bf(v0.y) << 16)
      | ((unsigned long long)f2bf(v0.z) << 32)
      | ((unsigned long long)f2bf(v0.w) << 48);
  unsigned long long p1 = (unsigned long long)f2bf(v1.x)
      | ((unsigned long long)f2bf(v1.y) << 16)
      | ((unsigned long long)f2bf(v1.z) << 32)
      | ((unsigned long long)f2bf(v1.w) << 48);
  unsigned long long* dst = (unsigned long long*)(Ws + ((size_t)g << 16) + (kk << 10) + (nr << 5) + (hi << 3));
  dst[0] = p0;
  dst[1] = p1;
}

// ---------------- initial h -> hist slot 0 ----------------
__global__ void init_state_kernel(const float* __restrict__ h0in,
                                  unsigned short* h0s0, unsigned short* h1s0) {
  int i = blockIdx.x * blockDim.x + threadIdx.x;  // < BH
  h0s0[i] = f2bf(h0in[i]);
  h1s0[i] = f2bf(h0in[BH + i]);
}

// tid0-only: spin until the 8 sub-counters (256B apart) sum to 128
__device__ __forceinline__ void poll128(int* base) {
  for (;;) {
    int s = 0;
#pragma unroll
    for (int j = 0; j < 8; j++)
      s += __hip_atomic_load(base + (j << 6), __ATOMIC_RELAXED, __HIP_MEMORY_SCOPE_AGENT);
    if (s >= 128) return;
    __builtin_amdgcn_s_sleep(1);
  }
}

// ---------------- persistent 2-layer LSTM, v4 ----------------
// 256 blocks x 512 threads, 1 block/CU. Blocks 0-127: layer0, 128-255: layer1.
// Weights resident in LDS [kk][nrow][hi][16B]. h via write-once history
// (plain cached loads, packed sc1 stores). The dependency-free operand
// (L0: x_t, L1: h0out) lives ENTIRELY in registers (xa/xb, 32 frags),
// prefetched in the PREVIOUS step. Publish uses COUNTED vmcnt(32): stores
// are issued before the prefetch, so the FIFO vmcnt retires stores and
// leaves the 32 prefetch loads in flight ACROSS the barrier (never drained
// on the critical path). d_out writes are non-temporal (no LLC pollution ->
// x stays LLC-resident). Waits (tid0 single-line polls + raw s_barrier):
//   L0@s: cnt0[s-1].   L1@s: cnt1[s-1], cnt0[s+1] (gate for next prefetch).
__global__ __launch_bounds__(512) void lstm_persist(
    const unsigned short* __restrict__ W0s, const unsigned short* __restrict__ W1s,
    const float* __restrict__ b0, const float* __restrict__ b1,
    const unsigned short* __restrict__ xbf,
    unsigned short* h0hist, unsigned short* h1hist,
    const float* __restrict__ c0in, float* out, int* cnt)
{
  __shared__ short8 wlds[8192];   // 128 KB: [kk 0..63][nrow 0..31][hi 0..3]
  const int tid = threadIdx.x;
  const int bid = blockIdx.x;
  const int layer = bid >> 7;
  const int g = bid & 127;

  const unsigned short* Ws = layer ? W1s : W0s;
  const float* bias = layer ? b1 : b0;
  int* const cnt0 = cnt;                  // cnt0[s], stride 512 ints
  int* const cnt1 = cnt + (530 << 9);     // cnt1[s], stride 512 ints

  // ---- stage weight slice once: linear 128KB copy ----
  {
    const short8* wsrc = (const short8*)(Ws + ((size_t)g << 16));
#pragma unroll
    for (int it = 0; it < 16; it++)
      wlds[tid + (it << 9)] = wsrc[tid + (it << 9)];
  }

  // ---- wave / lane mapping ----
  const int lane = tid & 63;
  const int w  = tid >> 6;        // 0..7
  const int mt = w & 3;           // m-tile (batch)
  const int nt = w >> 2;          // n-tile 0..1
  const int m0 = mt << 4;
  const int n  = lane & 15;
  const int hi = lane >> 4;
  const int q  = n >> 2;          // gate type of this lane's acc column
  const int jl = n & 3;
  const int jg = (g << 3) + (nt << 2) + jl;    // h column 0..1023
  const int nrow = (nt << 4) + n;              // weight row in slice
  const short8* bbase = wlds + ((nrow << 2) + hi);   // + kk*128 per fragment
  const int rowoff = ((m0 + n) << 10) + (hi << 3);   // A-row base (elements)

  // per-lane bias for this lane's own gate column
  const float blane = bias[(q << 10) + jg];

  // ---- c state in registers (lanes n<4 hold 4 values each) ----
  float creg[4];
  if (n < 4) {
#pragma unroll
    for (int r = 0; r < 4; r++) {
      int m = m0 + (hi << 2) + r;
      creg[r] = c0in[(size_t)layer * BH + (m << 10) + jg];
    }
  }
  __syncthreads();

  // ---- prologue: gate (L1) + preload step-0 dependency-free operand ----
  if (layer == 1) {
    if (tid == 0) poll128(cnt0);     // h0hist[1] complete
    __syncthreads();
  }
  short8 xa[16], xb[16];
  {
    const unsigned short* A0 = ((layer == 0) ? xbf : h0hist + (size_t)BH) + rowoff;
#pragma unroll
    for (int j = 0; j < 16; j++) xa[j] = *(const short8*)(A0 + (j << 5));
#pragma unroll
    for (int j = 0; j < 16; j++) xb[j] = *(const short8*)(A0 + ((16 + j) << 5));
  }

  for (int s = 0; s < TT; s++) {
    // ---------- PHASE A: dependency-free operand (regs) x first K-half ----------
    f32x4 acc = {0.0f, 0.0f, 0.0f, 0.0f};
#pragma unroll
    for (int j = 0; j < 16; j++)
      acc = __builtin_amdgcn_mfma_f32_16x16x32_bf16(xa[j], bbase[j << 7], acc, 0, 0, 0);
#pragma unroll
    for (int j = 0; j < 16; j++)
      acc = __builtin_amdgcn_mfma_f32_16x16x32_bf16(xb[j], bbase[(16 + j) << 7], acc, 0, 0, 0);

    // ---------- wait (tid0 polls; raw s_barrier, no drain) ----------
    if (tid == 0) {
      if (layer == 0) {
        if (s >= 1) poll128(cnt0 + ((s - 1) << 9));
      } else {
        if (s >= 1) poll128(cnt1 + ((s - 1) << 9));
        if (s + 1 < TT) poll128(cnt0 + ((s + 1) << 9));  // gate for next prefetch
      }
    }
    __builtin_amdgcn_s_barrier();

    // ---------- PHASE B: own-layer h x second K-half (8-deep rolling) ----------
    const unsigned short* inB = ((layer == 0) ? h0hist + (size_t)s * BH
                                              : h1hist + (size_t)s * BH) + rowoff;
    short8 ha[8];
#pragma unroll
    for (int j = 0; j < 8; j++) ha[j] = *(const short8*)(inB + (j << 5));
#pragma unroll
    for (int blk = 0; blk < 4; blk++) {
#pragma unroll
      for (int j = 0; j < 8; j++) {
        acc = __builtin_amdgcn_mfma_f32_16x16x32_bf16(ha[j], bbase[(32 + (blk << 3) + j) << 7], acc, 0, 0, 0);
        if (blk < 3) ha[j] = *(const short8*)(inB + ((((blk + 1) << 3) + j) << 5));
      }
    }

    // ---------- epilogue: all-lane activation, gather, state update, stores ----------
    unsigned short* hb = ((layer == 0) ? h0hist : h1hist) + (size_t)(s + 1) * BH;
    unsigned int* hb32 = (unsigned int*)hb;
    float* hf = nullptr;
    if (layer == 1) hf = out + (size_t)s * BH;              // hlast[s]
    else if (s == TT - 1) hf = out + (size_t)TT * BH;       // final h, layer 0

    const int src = (lane & 48) | jl;
#pragma unroll
    for (int r = 0; r < 4; r++) {
      // single-exp branchless activation on ALL lanes (q==2 -> tanh, else sigmoid)
      float a = acc[r] + blane;
      float t = (q == 2) ? (a + a) : -a;
      float e = __expf(t);
      float act = (q == 2) ? (1.0f - 2.0f / (e + 1.0f)) : (1.0f / (1.0f + e));
      float vi = __shfl(act, src,      64);
      float vf = __shfl(act, src | 4,  64);
      float vg = __shfl(act, src | 8,  64);
      float vo = __shfl(act, src | 12, 64);
      float hn = 0.f;
      int m = m0 + (hi << 2) + r;
      int idx = (m << 10) + jg;
      if (n < 4) {
        float cn = vi * vg + vf * creg[r];
        hn = vo * ftanhf(cn);
        creg[r] = cn;
        if (layer == 1 && s == TT - 1) {
          out[(size_t)TT * BH + BH + idx] = hn;        // final h, layer 1
          out[(size_t)TT * BH + 3 * BH + idx] = cn;    // final c, layer 1
        }
        if (layer == 0 && s == TT - 1) {
          out[(size_t)TT * BH + 2 * BH + idx] = cn;    // final c, layer 0
        }
      }
      float hn2 = __shfl(hn, lane + 1, 64);
      if (n < 4 && (n & 1) == 0) {
        unsigned int pack = (unsigned int)f2bf(hn) | ((unsigned int)f2bf(hn2) << 16);
        __hip_atomic_store(hb32 + (idx >> 1), pack, __ATOMIC_RELAXED, __HIP_MEMORY_SCOPE_AGENT);
        if (hf) {  // non-temporal: d_out is never re-read -> don't pollute LLC
          __builtin_nontemporal_store(hn,  hf + idx);
          __builtin_nontemporal_store(hn2, hf + idx + 1);
        }
      }
    }

    // ---------- prefetch next step's dependency-free operand (AFTER stores) ----------
    asm volatile("" ::: "memory");   // pin order: stores older than prefetch loads
    if (s + 1 < TT) {
      const unsigned short* nA = ((layer == 0) ? xbf + (size_t)(s + 1) * BH
                                               : h0hist + (size_t)(s + 2) * BH) + rowoff;
#pragma unroll
      for (int j = 0; j < 16; j++) xa[j] = *(const short8*)(nA + (j << 5));
#pragma unroll
      for (int j = 0; j < 16; j++) xb[j] = *(const short8*)(nA + ((16 + j) << 5));
    }

    // ---------- publish: counted-vmcnt drain (stores only), raw barrier, 1 atomicAdd ----------
    if (s + 1 < TT) {
      asm volatile("s_waitcnt vmcnt(32)" ::: "memory");  // retire stores; keep 32 prefetch loads in flight
    } else {
      asm volatile("s_waitcnt vmcnt(0)" ::: "memory");   // last iter: full drain
    }
    __builtin_amdgcn_sched_barrier(0);
    __builtin_amdgcn_s_barrier();
    if (tid == 0) {
      int* c = (layer == 0) ? cnt0 : cnt1;
      atomicAdd(c + (s << 9) + ((g & 7) << 6), 1);
    }
  }
}

extern "C" void kernel_launch(void* const* d_in, const int* in_sizes, int n_in,
                              void* d_out, int out_size, void* d_ws, size_t ws_size,
                              hipStream_t stream) {
  (void)in_sizes; (void)n_in; (void)out_size; (void)ws_size;
  const float* x    = (const float*)d_in[0];
  const float* h0in = (const float*)d_in[1];
  const float* c0in = (const float*)d_in[2];
  const float* W0   = (const float*)d_in[3];
  const float* b0   = (const float*)d_in[4];
  const float* W1   = (const float*)d_in[5];
  const float* b1   = (const float*)d_in[6];
  float* out = (float*)d_out;

  char* ws = (char*)d_ws;
  const size_t HIST = (size_t)(TT + 1) * BH * sizeof(unsigned short);  // 67,239,936 B
  unsigned short* Xbf    = (unsigned short*)(ws);                      // 64 MB
  unsigned short* W0s    = (unsigned short*)(ws + 67108864);           // 16 MB
  unsigned short* W1s    = (unsigned short*)(ws + 83886080);           // 16 MB
  unsigned short* h0hist = (unsigned short*)(ws + 100663296);          // 64.1 MB
  unsigned short* h1hist = (unsigned short*)(ws + 100663296 + HIST);   // 64.1 MB
  int* cnt               = (int*)(ws + 100663296 + 2 * HIST);          // ~2.2 MB

  const size_t CNT_BYTES = (size_t)(530 + TT) * 512 * sizeof(int);
  hipMemsetAsync(cnt, 0, CNT_BYTES, stream);
  cvt_x_kernel<<<2048, 256, 0, stream>>>(x, Xbf);
  cvt_w_kernel<<<4096, 256, 0, stream>>>(W0, W0s);
  cvt_w_kernel<<<4096, 256, 0, stream>>>(W1, W1s);
  init_state_kernel<<<256, 256, 0, stream>>>(h0in, h0hist, h1hist);

  lstm_persist<<<256, 512, 0, stream>>>(W0s, W1s, b0, b1, Xbf,
                                        h0hist, h1hist, c0in, out, cnt);
}

// Round 10
// 10121.262 us; speedup vs baseline: 1.0007x; 1.0007x over previous
//
#include <hip/hip_runtime.h>
#include <hip/hip_bf16.h>
#include <stdint.h>

// Problem constants (fixed by the reference): T=512, B=64, IN=H=1024, L=2
#define TT 512
#define BB 64
#define HH 1024
#define BH 65536    // B*H elements
#define KD 2048     // IN+H == H+H

typedef __attribute__((ext_vector_type(8))) short short8;
typedef __attribute__((ext_vector_type(4))) float f32x4;

__device__ __forceinline__ unsigned short f2bf(float f) {
  union { float f; unsigned int u; } v; v.f = f;
  unsigned int r = v.u + 0x7fffu + ((v.u >> 16) & 1u);  // RNE
  return (unsigned short)(r >> 16);
}
__device__ __forceinline__ float bf2f(unsigned short u) {
  union { unsigned int u; float f; } v; v.u = ((unsigned int)u) << 16; return v.f;
}
__device__ __forceinline__ float ftanhf(float x){ return 1.0f - 2.0f / (__expf(2.0f * x) + 1.0f); }

// ---------------- x -> bf16 ----------------
__global__ void cvt_x_kernel(const float* __restrict__ x, unsigned short* __restrict__ xbf) {
  const int n4 = (TT * BB * 1024) / 4;
  int stride = gridDim.x * blockDim.x;
  for (int i = blockIdx.x * blockDim.x + threadIdx.x; i < n4; i += stride) {
    float4 v = ((const float4*)x)[i];
    unsigned long long p = (unsigned long long)f2bf(v.x)
        | ((unsigned long long)f2bf(v.y) << 16)
        | ((unsigned long long)f2bf(v.z) << 32)
        | ((unsigned long long)f2bf(v.w) << 48);
    ((unsigned long long*)xbf)[i] = p;
  }
}

// ---------------- W [4096][2048] f32 -> bf16, LDS-image layout ----------------
// Ws[g][kk 0..63][nrow 0..31][hi 0..3][8 bf16]  (16B chunks; 128 KB per slice g)
__global__ void cvt_w_kernel(const float* __restrict__ W, unsigned short* __restrict__ Ws) {
  int idx = blockIdx.x * blockDim.x + threadIdx.x;   // < 128*64*32*4 = 1,048,576
  int hi = idx & 3;
  int nr = (idx >> 2) & 31;
  int kk = (idx >> 7) & 63;
  int g  = idx >> 13;
  int q  = (nr >> 2) & 3;
  int nt = nr >> 4;
  int jl = nr & 3;
  int grow = (q << 10) + (g << 3) + (nt << 2) + jl;
  int k = ((kk < 32) ? (kk << 5) : (1024 + ((kk - 32) << 5))) + (hi << 3);
  const float* src = W + (size_t)grow * KD + k;
  float4 v0 = ((const float4*)src)[0];
  float4 v1 = ((const float4*)src)[1];
  unsigned long long p0 = (unsigned long long)f2bf(v0.x)
      | ((unsigned long long)f2bf(v0.y) << 16)
      | ((unsigned long long)f2bf(v0.z) << 32)
      | ((unsigned long long)f2bf(v0.w) << 48);
  unsigned long long p1 = (unsigned long long)f2bf(v1.x)
      | ((unsigned long long)f2bf(v1.y) << 16)
      | ((unsigned long long)f2bf(v1.z) << 32)
      | ((unsigned long long)f2bf(v1.w) << 48);
  unsigned long long* dst = (unsigned long long*)(Ws + ((size_t)g << 16) + (kk << 10) + (nr << 5) + (hi << 3));
  dst[0] = p0;
  dst[1] = p1;
}

// ---------------- initial h -> hist slot 0 ----------------
__global__ void init_state_kernel(const float* __restrict__ h0in,
                                  unsigned short* h0s0, unsigned short* h1s0) {
  int i = blockIdx.x * blockDim.x + threadIdx.x;  // < BH
  h0s0[i] = f2bf(h0in[i]);
  h1s0[i] = f2bf(h0in[BH + i]);
}

// ---------------- post-pass: hist (bf16) -> out (fp32) ----------------
// out[e] for e in [0, TT*BH)            = h1hist[e + BH]   (hlast[t] = h1 after t+1 steps)
//        e in [TT*BH, TT*BH+BH)         = h0hist[e]        (final h layer 0, slot TT)
//        e in [TT*BH+BH, TT*BH+2BH)     = h1hist[e - BH]   (final h layer 1, slot TT)
__global__ void finalize_kernel(const unsigned short* __restrict__ h0hist,
                                const unsigned short* __restrict__ h1hist,
                                float* __restrict__ out) {
  const size_t N = (size_t)(TT + 2) * BH / 4;
  size_t stride = (size_t)gridDim.x * blockDim.x;
  for (size_t i = (size_t)blockIdx.x * blockDim.x + threadIdx.x; i < N; i += stride) {
    size_t e = i * 4;
    const unsigned short* src;
    if (e < (size_t)TT * BH) src = h1hist + e + BH;
    else if (e < (size_t)TT * BH + BH) src = h0hist + e;
    else src = h1hist + e - BH;
    ushort4 v = *(const ushort4*)src;
    float4 f = make_float4(bf2f(v.x), bf2f(v.y), bf2f(v.z), bf2f(v.w));
    *(float4*)(out + e) = f;
  }
}

// tid0-only: spin until the 8 sub-counters (256B apart) sum to 128
__device__ __forceinline__ void poll128(int* base) {
  for (;;) {
    int s = 0;
#pragma unroll
    for (int j = 0; j < 8; j++)
      s += __hip_atomic_load(base + (j << 6), __ATOMIC_RELAXED, __HIP_MEMORY_SCOPE_AGENT);
    if (s >= 128) return;
    __builtin_amdgcn_s_sleep(1);
  }
}

// ---------------- persistent 2-layer LSTM, v5 ----------------
// 256 blocks x 512 threads, 1 block/CU. Blocks 0-127: layer0, 128-255: layer1.
// Weights resident in LDS [kk][nrow][hi][16B]. h via write-once history
// (plain cached dwordx4 loads, packed-2xbf16 sc1 stores). Dependency-free
// operand (L0: x_t, L1: h0out) register-resident, prefetched previous step.
// NEW: LLC WRITE-ALLOCATE WARMING — each wave issues one sc1 dummy-load for
// its block's slot-(s+2) h lines (L2-bypassing, preserves write-once plain-read
// invariant) so the epilogue's partial-line sc1 stores merge at LLC-hit speed
// instead of stalling the drain on synchronized HBM line fetches. tid0's wave
// also warms step-(s+3) counter lines. No fp32 out stores in the loop (post-
// pass finalize_kernel). Publish: [4 sc1 stores][warms][32 prefetch loads],
// s_waitcnt vmcnt(32) -> retires stores+warms, keeps prefetches in flight
// across the raw s_barrier; tid0 atomicAdd to 8-way-split counter.
__global__ __launch_bounds__(512) void lstm_persist(
    const unsigned short* __restrict__ W0s, const unsigned short* __restrict__ W1s,
    const float* __restrict__ b0, const float* __restrict__ b1,
    const unsigned short* __restrict__ xbf,
    unsigned short* h0hist, unsigned short* h1hist,
    const float* __restrict__ c0in, float* out, int* cnt)
{
  __shared__ short8 wlds[8192];   // 128 KB: [kk 0..63][nrow 0..31][hi 0..3]
  const int tid = threadIdx.x;
  const int bid = blockIdx.x;
  const int layer = bid >> 7;
  const int g = bid & 127;

  const unsigned short* Ws = layer ? W1s : W0s;
  const float* bias = layer ? b1 : b0;
  int* const cnt0 = cnt;                  // cnt0[s], stride 512 ints
  int* const cnt1 = cnt + (530 << 9);     // cnt1[s], stride 512 ints

  // ---- stage weight slice once: linear 128KB copy ----
  {
    const short8* wsrc = (const short8*)(Ws + ((size_t)g << 16));
#pragma unroll
    for (int it = 0; it < 16; it++)
      wlds[tid + (it << 9)] = wsrc[tid + (it << 9)];
  }

  // ---- wave / lane mapping ----
  const int lane = tid & 63;
  const int w  = tid >> 6;        // 0..7
  const int mt = w & 3;           // m-tile (batch)
  const int nt = w >> 2;          // n-tile 0..1
  const int m0 = mt << 4;
  const int n  = lane & 15;
  const int hi = lane >> 4;
  const int q  = n >> 2;          // gate type of this lane's acc column
  const int jl = n & 3;
  const int jg = (g << 3) + (nt << 2) + jl;    // h column 0..1023
  const int nrow = (nt << 4) + n;              // weight row in slice
  const short8* bbase = wlds + ((nrow << 2) + hi);   // + kk*128 per fragment
  const int rowoff = ((m0 + n) << 10) + (hi << 3);   // A-row base (elements)

  // per-lane bias for this lane's own gate column
  const float blane = bias[(q << 10) + jg];

  unsigned short* const myhist = (layer == 0) ? h0hist : h1hist;

  // ---- c state in registers (lanes n<4 hold 4 values each) ----
  float creg[4];
  if (n < 4) {
#pragma unroll
    for (int r = 0; r < 4; r++) {
      int m = m0 + (hi << 2) + r;
      creg[r] = c0in[(size_t)layer * BH + (m << 10) + jg];
    }
  }
  __syncthreads();

  // ---- prologue: gate (L1) + preload step-0 dependency-free operand ----
  if (layer == 1) {
    if (tid == 0) poll128(cnt0);     // h0hist[1] complete
    __syncthreads();
  }
  short8 xa[16], xb[16];
  {
    const unsigned short* A0 = ((layer == 0) ? xbf : h0hist + (size_t)BH) + rowoff;
#pragma unroll
    for (int j = 0; j < 16; j++) xa[j] = *(const short8*)(A0 + (j << 5));
#pragma unroll
    for (int j = 0; j < 16; j++) xb[j] = *(const short8*)(A0 + ((16 + j) << 5));
  }

  for (int s = 0; s < TT; s++) {
    // ---------- PHASE A: dependency-free operand (regs) x first K-half ----------
    f32x4 acc = {0.0f, 0.0f, 0.0f, 0.0f};
#pragma unroll
    for (int j = 0; j < 16; j++)
      acc = __builtin_amdgcn_mfma_f32_16x16x32_bf16(xa[j], bbase[j << 7], acc, 0, 0, 0);
#pragma unroll
    for (int j = 0; j < 16; j++)
      acc = __builtin_amdgcn_mfma_f32_16x16x32_bf16(xb[j], bbase[(16 + j) << 7], acc, 0, 0, 0);

    // ---------- wait (tid0 polls; raw s_barrier, no drain) ----------
    if (tid == 0) {
      if (layer == 0) {
        if (s >= 1) poll128(cnt0 + ((s - 1) << 9));
      } else {
        if (s >= 1) poll128(cnt1 + ((s - 1) << 9));
        if (s + 1 < TT) poll128(cnt0 + ((s + 1) << 9));  // gate for next prefetch
      }
    }
    __builtin_amdgcn_s_barrier();

    // ---------- PHASE B: own-layer h x second K-half (8-deep rolling) ----------
    const unsigned short* inB = myhist + (size_t)s * BH + rowoff;
    short8 ha[8];
#pragma unroll
    for (int j = 0; j < 8; j++) ha[j] = *(const short8*)(inB + (j << 5));
#pragma unroll
    for (int blk = 0; blk < 4; blk++) {
#pragma unroll
      for (int j = 0; j < 8; j++) {
        acc = __builtin_amdgcn_mfma_f32_16x16x32_bf16(ha[j], bbase[(32 + (blk << 3) + j) << 7], acc, 0, 0, 0);
        if (blk < 3) ha[j] = *(const short8*)(inB + ((((blk + 1) << 3) + j) << 5));
      }
    }

    // ---------- epilogue: all-lane activation, gather, state update, h stores ----------
    unsigned int* hb32 = (unsigned int*)(myhist + (size_t)(s + 1) * BH);

    const int src = (lane & 48) | jl;
#pragma unroll
    for (int r = 0; r < 4; r++) {
      // single-exp branchless activation on ALL lanes (q==2 -> tanh, else sigmoid)
      float a = acc[r] + blane;
      float t = (q == 2) ? (a + a) : -a;
      float e = __expf(t);
      float act = (q == 2) ? (1.0f - 2.0f / (e + 1.0f)) : (1.0f / (1.0f + e));
      float vi = __shfl(act, src,      64);
      float vf = __shfl(act, src | 4,  64);
      float vg = __shfl(act, src | 8,  64);
      float vo = __shfl(act, src | 12, 64);
      float hn = 0.f;
      int m = m0 + (hi << 2) + r;
      int idx = (m << 10) + jg;
      if (n < 4) {
        float cn = vi * vg + vf * creg[r];
        hn = vo * ftanhf(cn);
        creg[r] = cn;
        if (s == TT - 1) {   // final c, layers 0/1 (tiny, once; drained by vmcnt(0))
          out[(size_t)TT * BH + (size_t)(2 + layer) * BH + idx] = cn;
        }
      }
      float hn2 = __shfl(hn, lane + 1, 64);
      if (n < 4 && (n & 1) == 0) {
        unsigned int pack = (unsigned int)f2bf(hn) | ((unsigned int)f2bf(hn2) << 16);
        __hip_atomic_store(hb32 + (idx >> 1), pack, __ATOMIC_RELAXED, __HIP_MEMORY_SCOPE_AGENT);
      }
    }

    // ---------- warm + prefetch (AFTER stores; FIFO: stores are oldest) ----------
    asm volatile("" ::: "memory");   // compiler barrier: pin store->load issue order
    if (s + 2 <= TT) {
      // warm this block's slot-(s+2) h lines: 8 lanes/wave x 8 waves = 64 rows.
      // sc1 load (L2-bypass): allocates line in LLC, does NOT cache in L2.
      if (lane < 8) {
        int mrow = (w << 3) + lane;
        const int* wa = (const int*)(myhist + (size_t)(s + 2) * BH + (mrow << 10) + ((g >> 3) << 6));
        int d = __hip_atomic_load(wa, __ATOMIC_RELAXED, __HIP_MEMORY_SCOPE_AGENT);
        asm volatile("" :: "v"(d));
      }
    }
    if (w == 0 && lane < 16 && s + 3 < TT) {
      // warm step-(s+3) counter lines (8 sub-lines each of cnt0/cnt1)
      int* cw = ((lane < 8) ? cnt0 : cnt1) + ((s + 3) << 9) + ((lane & 7) << 6);
      int d = __hip_atomic_load(cw, __ATOMIC_RELAXED, __HIP_MEMORY_SCOPE_AGENT);
      asm volatile("" :: "v"(d));
    }
    if (s + 1 < TT) {
      const unsigned short* nA = ((layer == 0) ? xbf + (size_t)(s + 1) * BH
                                               : h0hist + (size_t)(s + 2) * BH) + rowoff;
#pragma unroll
      for (int j = 0; j < 16; j++) xa[j] = *(const short8*)(nA + (j << 5));
#pragma unroll
      for (int j = 0; j < 16; j++) xb[j] = *(const short8*)(nA + ((16 + j) << 5));
    }

    // ---------- publish: counted-vmcnt drain (stores+warms), raw barrier, 1 atomicAdd ----------
    if (s + 1 < TT) {
      asm volatile("s_waitcnt vmcnt(32)" ::: "memory");  // retire 4 stores + warms; keep 32 prefetch loads in flight
    } else {
      asm volatile("s_waitcnt vmcnt(0)" ::: "memory");   // last iter: full drain
    }
    __builtin_amdgcn_sched_barrier(0);
    __builtin_amdgcn_s_barrier();
    if (tid == 0) {
      int* c = (layer == 0) ? cnt0 : cnt1;
      atomicAdd(c + (s << 9) + ((g & 7) << 6), 1);
    }
  }
}

extern "C" void kernel_launch(void* const* d_in, const int* in_sizes, int n_in,
                              void* d_out, int out_size, void* d_ws, size_t ws_size,
                              hipStream_t stream) {
  (void)in_sizes; (void)n_in; (void)out_size; (void)ws_size;
  const float* x    = (const float*)d_in[0];
  const float* h0in = (const float*)d_in[1];
  const float* c0in = (const float*)d_in[2];
  const float* W0   = (const float*)d_in[3];
  const float* b0   = (const float*)d_in[4];
  const float* W1   = (const float*)d_in[5];
  const float* b1   = (const float*)d_in[6];
  float* out = (float*)d_out;

  char* ws = (char*)d_ws;
  const size_t HIST = (size_t)(TT + 1) * BH * sizeof(unsigned short);  // 67,239,936 B
  unsigned short* Xbf    = (unsigned short*)(ws);                      // 64 MB
  unsigned short* W0s    = (unsigned short*)(ws + 67108864);           // 16 MB
  unsigned short* W1s    = (unsigned short*)(ws + 83886080);           // 16 MB
  unsigned short* h0hist = (unsigned short*)(ws + 100663296);          // 64.1 MB
  unsigned short* h1hist = (unsigned short*)(ws + 100663296 + HIST);   // 64.1 MB
  int* cnt               = (int*)(ws + 100663296 + 2 * HIST);          // ~2.2 MB

  const size_t CNT_BYTES = (size_t)(530 + TT + 4) * 512 * sizeof(int);
  hipMemsetAsync(cnt, 0, CNT_BYTES, stream);
  cvt_x_kernel<<<2048, 256, 0, stream>>>(x, Xbf);
  cvt_w_kernel<<<4096, 256, 0, stream>>>(W0, W0s);
  cvt_w_kernel<<<4096, 256, 0, stream>>>(W1, W1s);
  init_state_kernel<<<256, 256, 0, stream>>>(h0in, h0hist, h1hist);

  lstm_persist<<<256, 512, 0, stream>>>(W0s, W1s, b0, b1, Xbf,
                                        h0hist, h1hist, c0in, out, cnt);

  finalize_kernel<<<4096, 256, 0, stream>>>(h0hist, h1hist, out);
}

// Round 11
// 8357.940 us; speedup vs baseline: 1.2118x; 1.2110x over previous
//
#include <hip/hip_runtime.h>
#include <hip/hip_bf16.h>
#include <stdint.h>

// Problem constants (fixed by the reference): T=512, B=64, IN=H=1024, L=2
#define TT 512
#define BB 64
#define HH 1024
#define BH 65536    // B*H elements
#define KD 2048     // IN+H == H+H

typedef __attribute__((ext_vector_type(8))) short short8;
typedef __attribute__((ext_vector_type(4))) float f32x4;

__device__ __forceinline__ unsigned short f2bf(float f) {
  union { float f; unsigned int u; } v; v.f = f;
  unsigned int r = v.u + 0x7fffu + ((v.u >> 16) & 1u);  // RNE
  return (unsigned short)(r >> 16);
}
__device__ __forceinline__ float ftanhf(float x){ return 1.0f - 2.0f / (__expf(2.0f * x) + 1.0f); }

// ---------------- x -> bf16 ----------------
__global__ void cvt_x_kernel(const float* __restrict__ x, unsigned short* __restrict__ xbf) {
  const int n4 = (TT * BB * 1024) / 4;
  int stride = gridDim.x * blockDim.x;
  for (int i = blockIdx.x * blockDim.x + threadIdx.x; i < n4; i += stride) {
    float4 v = ((const float4*)x)[i];
    unsigned long long p = (unsigned long long)f2bf(v.x)
        | ((unsigned long long)f2bf(v.y) << 16)
        | ((unsigned long long)f2bf(v.z) << 32)
        | ((unsigned long long)f2bf(v.w) << 48);
    ((unsigned long long*)xbf)[i] = p;
  }
}

// ---------------- W [4096][2048] f32 -> bf16, LDS-image layout ----------------
// Ws[g][kk 0..63][nrow 0..31][hi 0..3][8 bf16]  (16B chunks; 128 KB per slice g)
__global__ void cvt_w_kernel(const float* __restrict__ W, unsigned short* __restrict__ Ws) {
  int idx = blockIdx.x * blockDim.x + threadIdx.x;   // < 128*64*32*4 = 1,048,576
  int hi = idx & 3;
  int nr = (idx >> 2) & 31;
  int kk = (idx >> 7) & 63;
  int g  = idx >> 13;
  int q  = (nr >> 2) & 3;
  int nt = nr >> 4;
  int jl = nr & 3;
  int grow = (q << 10) + (g << 3) + (nt << 2) + jl;
  int k = ((kk < 32) ? (kk << 5) : (1024 + ((kk - 32) << 5))) + (hi << 3);
  const float* src = W + (size_t)grow * KD + k;
  float4 v0 = ((const float4*)src)[0];
  float4 v1 = ((const float4*)src)[1];
  unsigned long long p0 = (unsigned long long)f2bf(v0.x)
      | ((unsigned long long)f2bf(v0.y) << 16)
      | ((unsigned long long)f2bf(v0.z) << 32)
      | ((unsigned long long)f2bf(v0.w) << 48);
  unsigned long long p1 = (unsigned long long)f2bf(v1.x)
      | ((unsigned long long)f2bf(v1.y) << 16)
      | ((unsigned long long)f2bf(v1.z) << 32)
      | ((unsigned long long)f2bf(v1.w) << 48);
  unsigned long long* dst = (unsigned long long*)(Ws + ((size_t)g << 16) + (kk << 10) + (nr << 5) + (hi << 3));
  dst[0] = p0;
  dst[1] = p1;
}

// ---------------- initial h -> hist slot 0 ----------------
__global__ void init_state_kernel(const float* __restrict__ h0in,
                                  unsigned short* h0s0, unsigned short* h1s0) {
  int i = blockIdx.x * blockDim.x + threadIdx.x;  // < BH
  h0s0[i] = f2bf(h0in[i]);
  h1s0[i] = f2bf(h0in[BH + i]);
}

#define GLD(p)    __hip_atomic_load((p),  __ATOMIC_RELAXED, __HIP_MEMORY_SCOPE_AGENT)
#define GST(p, v) __hip_atomic_store((p), (v), __ATOMIC_RELAXED, __HIP_MEMORY_SCOPE_AGENT)

// ---------------- persistent 2-layer LSTM, v6: mailbox-broadcast sync ----------------
// 256 blocks x 512 threads, 1 block/CU. Blocks 0-127: layer0, 128-255: layer1.
// Data path identical to v3/r8 (proven fastest): weights in LDS [kk][nrow][hi],
// write-once h history (plain cached dwordx4 loads, packed-2xbf16 sc1 stores),
// register-resident dependency-free operand prefetched a step ahead.
// SYNC v6: producers atomicAdd 8-way-split cnt[L][s] as before, but each cnt
// is polled by EXACTLY ONE wave on the whole GPU (wave0 of block 0 for cnt0,
// wave0 of block 128 for cnt1; 64-lane load + shfl_xor reduce). On detect it
// broadcasts step number to per-consumer PRIVATE mailbox lines (128B apart,
// monotone): go0[j] j<256 (j=g for L0, 128+g for L1 gate), go1[j] j<128.
// Consumers poll only their own line -> 1 poller/line, zero LLC contention.
// No s_sleep anywhere (DVFS hedge; dependent-load latency throttles polls).
__global__ __launch_bounds__(512) void lstm_persist(
    const unsigned short* __restrict__ W0s, const unsigned short* __restrict__ W1s,
    const float* __restrict__ b0, const float* __restrict__ b1,
    const unsigned short* __restrict__ xbf,
    unsigned short* h0hist, unsigned short* h1hist,
    const float* __restrict__ c0in, float* out, int* cnt)
{
  __shared__ short8 wlds[8192];   // 128 KB: [kk 0..63][nrow 0..31][hi 0..3]
  const int tid = threadIdx.x;
  const int bid = blockIdx.x;
  const int layer = bid >> 7;
  const int g = bid & 127;

  const unsigned short* Ws = layer ? W1s : W0s;
  const float* bias = layer ? b1 : b0;
  int* const cnt0 = cnt;                  // cnt0[s], stride 512 ints (8 sub-lines)
  int* const cnt1 = cnt + (530 << 9);     // cnt1[s], stride 512 ints
  int* const go0  = cnt + (1048 << 9);    // 256 mailboxes, stride 32 ints (128B)
  int* const go1  = go0 + (256 << 5);     // 128 mailboxes

  // ---- stage weight slice once: linear 128KB copy ----
  {
    const short8* wsrc = (const short8*)(Ws + ((size_t)g << 16));
#pragma unroll
    for (int it = 0; it < 16; it++)
      wlds[tid + (it << 9)] = wsrc[tid + (it << 9)];
  }

  // ---- wave / lane mapping ----
  const int lane = tid & 63;
  const int w  = tid >> 6;        // 0..7
  const int mt = w & 3;           // m-tile (batch)
  const int nt = w >> 2;          // n-tile 0..1
  const int m0 = mt << 4;
  const int n  = lane & 15;
  const int hi = lane >> 4;
  const int q  = n >> 2;          // gate type of this lane's acc column
  const int jl = n & 3;
  const int jg = (g << 3) + (nt << 2) + jl;    // h column 0..1023
  const int nrow = (nt << 4) + n;              // weight row in slice
  const short8* bbase = wlds + ((nrow << 2) + hi);   // + kk*128 per fragment
  const int rowoff = ((m0 + n) << 10) + (hi << 3);   // A-row base (elements)

  const float blane = bias[(q << 10) + jg];
  unsigned short* const myhist = (layer == 0) ? h0hist : h1hist;

  // ---- c state in registers (lanes n<4 hold 4 values each) ----
  float creg[4];
  if (n < 4) {
#pragma unroll
    for (int r = 0; r < 4; r++) {
      int m = m0 + (hi << 2) + r;
      creg[r] = c0in[(size_t)layer * BH + (m << 10) + jg];
    }
  }
  __syncthreads();

  // ---- prologue: gate (L1) + preload step-0 dependency-free operand ----
  if (layer == 1) {
    if (bid == 128 && w == 0) {
      // agg1's wave directly detects cnt0[0] (it is the only L1 block without
      // a dedicated need; go0[128+0] is still its mailbox — poll it like others)
      if (lane == 0) { while (GLD(go0 + ((128 + g) << 5)) < 1) {} }
    } else if (tid == 0) {
      while (GLD(go0 + ((128 + g) << 5)) < 1) {}
    }
    __syncthreads();
  }
  short8 xa[16], xb[16];
  {
    const unsigned short* A0 = ((layer == 0) ? xbf : h0hist + (size_t)BH) + rowoff;
#pragma unroll
    for (int j = 0; j < 16; j++) xa[j] = *(const short8*)(A0 + (j << 5));
#pragma unroll
    for (int j = 0; j < 16; j++) xb[j] = *(const short8*)(A0 + ((16 + j) << 5));
  }

  for (int s = 0; s < TT; s++) {
    // ---------- PHASE A: dependency-free operand (regs) x first K-half ----------
    f32x4 acc = {0.0f, 0.0f, 0.0f, 0.0f};
#pragma unroll
    for (int j = 0; j < 16; j++)
      acc = __builtin_amdgcn_mfma_f32_16x16x32_bf16(xa[j], bbase[j << 7], acc, 0, 0, 0);
#pragma unroll
    for (int j = 0; j < 16; j++)
      acc = __builtin_amdgcn_mfma_f32_16x16x32_bf16(xb[j], bbase[(16 + j) << 7], acc, 0, 0, 0);

    // ---------- wait: aggregator detect+broadcast / consumer mailbox poll ----------
    if (s >= 1) {
      if (bid == 0) {
        if (w == 0) {          // sole poller of cnt0: detect cnt0[s-1] == 128
          int* base = cnt0 + ((s - 1) << 9) + ((lane & 7) << 6);
          for (;;) {
            int v = GLD(base);
#pragma unroll
            for (int m2 = 1; m2 < 64; m2 <<= 1) v += __shfl_xor(v, m2, 64);
            if (v >= 1024) break;   // 8 dup loads per sub-line x 128
          }
#pragma unroll
          for (int k2 = 0; k2 < 4; k2++) GST(go0 + ((lane | (k2 << 6)) << 5), s);
        }
      } else if (bid == 128) {
        if (w == 0) {          // sole poller of cnt1: detect cnt1[s-1] == 128
          int* base = cnt1 + ((s - 1) << 9) + ((lane & 7) << 6);
          for (;;) {
            int v = GLD(base);
#pragma unroll
            for (int m2 = 1; m2 < 64; m2 <<= 1) v += __shfl_xor(v, m2, 64);
            if (v >= 1024) break;
          }
#pragma unroll
          for (int k2 = 0; k2 < 2; k2++) GST(go1 + ((lane | (k2 << 6)) << 5), s);
        }
      } else if (tid == 0) {
        int* mb = (layer == 0) ? (go0 + (g << 5)) : (go1 + (g << 5));
        while (GLD(mb) < s) {}
      }
    }
    // L1 prefetch gate: h0hist[s+2] ready <=> cnt0[s+1] done <=> go0 >= s+2
    if (layer == 1 && s + 1 < TT && tid == 0) {
      while (GLD(go0 + ((128 + g) << 5)) < s + 2) {}
    }
    __syncthreads();

    // ---------- PHASE B: own-layer h x second K-half (8-deep rolling) ----------
    const unsigned short* inB = myhist + (size_t)s * BH + rowoff;
    short8 ha[8];
#pragma unroll
    for (int j = 0; j < 8; j++) ha[j] = *(const short8*)(inB + (j << 5));
#pragma unroll
    for (int blk = 0; blk < 4; blk++) {
#pragma unroll
      for (int j = 0; j < 8; j++) {
        acc = __builtin_amdgcn_mfma_f32_16x16x32_bf16(ha[j], bbase[(32 + (blk << 3) + j) << 7], acc, 0, 0, 0);
        if (blk < 3) ha[j] = *(const short8*)(inB + ((((blk + 1) << 3) + j) << 5));
      }
    }

    // ---------- prefetch next step's dependency-free operand (overlaps epilogue) ----------
    if (s + 1 < TT) {
      const unsigned short* nA = ((layer == 0) ? xbf + (size_t)(s + 1) * BH
                                               : h0hist + (size_t)(s + 2) * BH) + rowoff;
#pragma unroll
      for (int j = 0; j < 16; j++) xa[j] = *(const short8*)(nA + (j << 5));
#pragma unroll
      for (int j = 0; j < 16; j++) xb[j] = *(const short8*)(nA + ((16 + j) << 5));
    }

    // ---------- epilogue: all-lane activation, gather, state update, stores ----------
    unsigned int* hb32 = (unsigned int*)(myhist + (size_t)(s + 1) * BH);
    float* hf = nullptr;
    if (layer == 1) hf = out + (size_t)s * BH;              // hlast[s]
    else if (s == TT - 1) hf = out + (size_t)TT * BH;       // final h, layer 0

    const int src = (lane & 48) | jl;
#pragma unroll
    for (int r = 0; r < 4; r++) {
      // single-exp branchless activation on ALL lanes (q==2 -> tanh, else sigmoid)
      float a = acc[r] + blane;
      float t = (q == 2) ? (a + a) : -a;
      float e = __expf(t);
      float act = (q == 2) ? (1.0f - 2.0f / (e + 1.0f)) : (1.0f / (1.0f + e));
      float vi = __shfl(act, src,      64);
      float vf = __shfl(act, src | 4,  64);
      float vg = __shfl(act, src | 8,  64);
      float vo = __shfl(act, src | 12, 64);
      float hn = 0.f;
      int m = m0 + (hi << 2) + r;
      int idx = (m << 10) + jg;
      if (n < 4) {
        float cn = vi * vg + vf * creg[r];
        hn = vo * ftanhf(cn);
        creg[r] = cn;
        if (layer == 1 && s == TT - 1) {
          out[(size_t)TT * BH + BH + idx] = hn;        // final h, layer 1
          out[(size_t)TT * BH + 3 * BH + idx] = cn;    // final c, layer 1
        }
        if (layer == 0 && s == TT - 1) {
          out[(size_t)TT * BH + 2 * BH + idx] = cn;    // final c, layer 0
        }
      }
      float hn2 = __shfl(hn, lane + 1, 64);
      if (n < 4 && (n & 1) == 0) {
        unsigned int pack = (unsigned int)f2bf(hn) | ((unsigned int)f2bf(hn2) << 16);
        GST(hb32 + (idx >> 1), pack);
        if (hf) *(float2*)(hf + idx) = make_float2(hn, hn2);
      }
    }

    // ---------- publish: drain stores (syncthreads), then 1 atomicAdd ----------
    __syncthreads();
    if (tid == 0) {
      int* c = (layer == 0) ? cnt0 : cnt1;
      atomicAdd(c + (s << 9) + ((g & 7) << 6), 1);
    }
  }

  // ---- agg0 post-loop: deliver go0 = TT for L1's final prefetch gates ----
  if (bid == 0 && w == 0) {
    int* base = cnt0 + ((TT - 1) << 9) + ((lane & 7) << 6);
    for (;;) {
      int v = GLD(base);
#pragma unroll
      for (int m2 = 1; m2 < 64; m2 <<= 1) v += __shfl_xor(v, m2, 64);
      if (v >= 1024) break;
    }
    GST(go0 + ((128 + lane) << 5), TT);
    GST(go0 + ((192 + lane) << 5), TT);
  }
}

extern "C" void kernel_launch(void* const* d_in, const int* in_sizes, int n_in,
                              void* d_out, int out_size, void* d_ws, size_t ws_size,
                              hipStream_t stream) {
  (void)in_sizes; (void)n_in; (void)out_size; (void)ws_size;
  const float* x    = (const float*)d_in[0];
  const float* h0in = (const float*)d_in[1];
  const float* c0in = (const float*)d_in[2];
  const float* W0   = (const float*)d_in[3];
  const float* b0   = (const float*)d_in[4];
  const float* W1   = (const float*)d_in[5];
  const float* b1   = (const float*)d_in[6];
  float* out = (float*)d_out;

  char* ws = (char*)d_ws;
  const size_t HIST = (size_t)(TT + 1) * BH * sizeof(unsigned short);  // 67,239,936 B
  unsigned short* Xbf    = (unsigned short*)(ws);                      // 64 MB
  unsigned short* W0s    = (unsigned short*)(ws + 67108864);           // 16 MB
  unsigned short* W1s    = (unsigned short*)(ws + 83886080);           // 16 MB
  unsigned short* h0hist = (unsigned short*)(ws + 100663296);          // 64.1 MB
  unsigned short* h1hist = (unsigned short*)(ws + 100663296 + HIST);   // 64.1 MB
  int* cnt               = (int*)(ws + 100663296 + 2 * HIST);          // cnt + mailboxes

  const size_t CNT_BYTES = ((size_t)(1048 << 9) + (256 << 5) + (128 << 5)) * sizeof(int);
  hipMemsetAsync(cnt, 0, CNT_BYTES, stream);
  cvt_x_kernel<<<2048, 256, 0, stream>>>(x, Xbf);
  cvt_w_kernel<<<4096, 256, 0, stream>>>(W0, W0s);
  cvt_w_kernel<<<4096, 256, 0, stream>>>(W1, W1s);
  init_state_kernel<<<256, 256, 0, stream>>>(h0in, h0hist, h1hist);

  lstm_persist<<<256, 512, 0, stream>>>(W0s, W1s, b0, b1, Xbf,
                                        h0hist, h1hist, c0in, out, cnt);
}

// Round 12
// 5806.831 us; speedup vs baseline: 1.7441x; 1.4393x over previous
//
#include <hip/hip_runtime.h>
#include <hip/hip_bf16.h>
#include <stdint.h>

// Problem constants (fixed by the reference): T=512, B=64, IN=H=1024, L=2
#define TT 512
#define BB 64
#define HH 1024
#define BH 65536    // B*H elements
#define KD 2048     // IN+H == H+H

typedef __attribute__((ext_vector_type(8))) short short8;
typedef __attribute__((ext_vector_type(4))) float f32x4;

__device__ __forceinline__ unsigned short f2bf(float f) {
  union { float f; unsigned int u; } v; v.f = f;
  unsigned int r = v.u + 0x7fffu + ((v.u >> 16) & 1u);  // RNE
  return (unsigned short)(r >> 16);
}
__device__ __forceinline__ float ftanhf(float x){ return 1.0f - 2.0f / (__expf(2.0f * x) + 1.0f); }

// ---------------- x -> bf16 ----------------
__global__ void cvt_x_kernel(const float* __restrict__ x, unsigned short* __restrict__ xbf) {
  const int n4 = (TT * BB * 1024) / 4;
  int stride = gridDim.x * blockDim.x;
  for (int i = blockIdx.x * blockDim.x + threadIdx.x; i < n4; i += stride) {
    float4 v = ((const float4*)x)[i];
    unsigned long long p = (unsigned long long)f2bf(v.x)
        | ((unsigned long long)f2bf(v.y) << 16)
        | ((unsigned long long)f2bf(v.z) << 32)
        | ((unsigned long long)f2bf(v.w) << 48);
    ((unsigned long long*)xbf)[i] = p;
  }
}

// ---------------- W [4096][2048] f32 -> bf16, LDS-image layout ----------------
// Ws[g][kk 0..63][nrow 0..31][hi 0..3][8 bf16]  (16B chunks; 128 KB per slice g)
__global__ void cvt_w_kernel(const float* __restrict__ W, unsigned short* __restrict__ Ws) {
  int idx = blockIdx.x * blockDim.x + threadIdx.x;   // < 128*64*32*4 = 1,048,576
  int hi = idx & 3;
  int nr = (idx >> 2) & 31;
  int kk = (idx >> 7) & 63;
  int g  = idx >> 13;
  int q  = (nr >> 2) & 3;
  int nt = nr >> 4;
  int jl = nr & 3;
  int grow = (q << 10) + (g << 3) + (nt << 2) + jl;
  int k = ((kk < 32) ? (kk << 5) : (1024 + ((kk - 32) << 5))) + (hi << 3);
  const float* src = W + (size_t)grow * KD + k;
  float4 v0 = ((const float4*)src)[0];
  float4 v1 = ((const float4*)src)[1];
  unsigned long long p0 = (unsigned long long)f2bf(v0.x)
      | ((unsigned long long)f2bf(v0.y) << 16)
      | ((unsigned long long)f2bf(v0.z) << 32)
      | ((unsigned long long)f2bf(v0.w) << 48);
  unsigned long long p1 = (unsigned long long)f2bf(v1.x)
      | ((unsigned long long)f2bf(v1.y) << 16)
      | ((unsigned long long)f2bf(v1.z) << 32)
      | ((unsigned long long)f2bf(v1.w) << 48);
  unsigned long long* dst = (unsigned long long*)(Ws + ((size_t)g << 16) + (kk << 10) + (nr << 5) + (hi << 3));
  dst[0] = p0;
  dst[1] = p1;
}

// ---------------- initial h -> hist slot 0 ----------------
__global__ void init_state_kernel(const float* __restrict__ h0in,
                                  unsigned short* h0s0, unsigned short* h1s0) {
  int i = blockIdx.x * blockDim.x + threadIdx.x;  // < BH
  h0s0[i] = f2bf(h0in[i]);
  h1s0[i] = f2bf(h0in[BH + i]);
}

#define GLD(p)    __hip_atomic_load((p),  __ATOMIC_RELAXED, __HIP_MEMORY_SCOPE_AGENT)
#define GST(p, v) __hip_atomic_store((p), (v), __ATOMIC_RELAXED, __HIP_MEMORY_SCOPE_AGENT)

// ---------------- persistent 2-layer LSTM, v7: producer/consumer wave split ----------------
// 256 blocks x 512 threads, 1 block/CU. Blocks 0-127: layer0, 128-255: layer1.
// Waves 0-3 (A-waves, mt=w): dependency-free GEMM (L0: x[s+1]; L1: h0[s+2],
// gated with 2-step slack). Dual n-tile accs -> f32x4 partials into LDS
// double-buffer pbuf[(s+1)&1]. One step ahead of consumers; never on the
// tight path (L0 A-waves wait on NOTHING).
// Waves 4-7 (B-waves, mt=w-4): tight recurrence: mailbox poll -> load own
// h[s] (32KB/wave, no duplication) -> 64 dual-acc MFMAs seeded from
// pbuf[s&1] -> epilogue -> packed sc1 h-store -> barrier -> publish.
// h via write-once history (plain cached loads). Sync = r11 mailbox:
// producers atomicAdd 8-way-split cnt[L][s]; single aggregator wave per
// layer (block0-w0 / block128-w0) detects 128 and broadcasts step to
// per-consumer private mailbox lines; consumers poll only their own line.
__global__ __launch_bounds__(512, 2) void lstm_persist(
    const unsigned short* __restrict__ W0s, const unsigned short* __restrict__ W1s,
    const float* __restrict__ b0, const float* __restrict__ b1,
    const unsigned short* __restrict__ xbf,
    unsigned short* h0hist, unsigned short* h1hist,
    const float* __restrict__ c0in, float* out, int* cnt)
{
  __shared__ short8 wlds[8192];            // 128 KB: [kk 0..63][nrow 0..31][hi 0..3]
  __shared__ f32x4 pbuf[2][4][2][64];      // 16 KB partial double-buffer
  const int tid = threadIdx.x;
  const int bid = blockIdx.x;
  const int layer = bid >> 7;
  const int g = bid & 127;

  const unsigned short* Ws = layer ? W1s : W0s;
  const float* bias = layer ? b1 : b0;
  int* const cnt0 = cnt;                  // cnt0[s], stride 512 ints (8 sub-lines)
  int* const cnt1 = cnt + (530 << 9);     // cnt1[s], stride 512 ints
  int* const go0  = cnt + (1048 << 9);    // 256 mailboxes, stride 32 ints (128B)
  int* const go1  = go0 + (256 << 5);     // 128 mailboxes

  // ---- stage weight slice once: linear 128KB copy ----
  {
    const short8* wsrc = (const short8*)(Ws + ((size_t)g << 16));
#pragma unroll
    for (int it = 0; it < 16; it++)
      wlds[tid + (it << 9)] = wsrc[tid + (it << 9)];
  }

  // ---- wave / lane mapping ----
  const int lane = tid & 63;
  const int w  = tid >> 6;        // 0..7
  const bool isA = (w < 4);
  const int mt = w & 3;           // m-tile (batch)
  const int m0 = mt << 4;
  const int n  = lane & 15;
  const int hi = lane >> 4;
  const int q  = n >> 2;          // gate type of this lane's acc column
  const int jl = n & 3;
  const int jgb = (g << 3) + jl;  // h column base (nt=0); nt=1 -> +4
  const short8* bbase0 = wlds + ((n << 2) + hi);          // n-tile 0 rows 0..15
  const short8* bbase1 = wlds + (((16 + n) << 2) + hi);   // n-tile 1 rows 16..31
  const int rowoff = ((m0 + n) << 10) + (hi << 3);        // A-row base (elements)

  unsigned short* const myhist = (layer == 0) ? h0hist : h1hist;

  // ---- B-wave state: biases + c registers for both n-tiles ----
  float creg[2][4];
  float blane0 = 0.f, blane1 = 0.f;
  if (!isA) {
    blane0 = bias[(q << 10) + jgb];
    blane1 = bias[(q << 10) + jgb + 4];
    if (n < 4) {
#pragma unroll
      for (int nt2 = 0; nt2 < 2; nt2++)
#pragma unroll
        for (int r = 0; r < 4; r++) {
          int m = m0 + (hi << 2) + r;
          creg[nt2][r] = c0in[(size_t)layer * BH + (m << 10) + jgb + (nt2 << 2)];
        }
    }
  }
  __syncthreads();   // weights staged

  // ---- prologue: A-waves compute partial[0] (L1 gated on go0 >= 1) ----
  if (isA) {
    if (layer == 1) { while (GLD(go0 + ((128 + g) << 5)) < 1) {} }
    const unsigned short* asrc = ((layer == 0) ? xbf : h0hist + (size_t)BH) + rowoff;
    short8 ha[8];
#pragma unroll
    for (int j = 0; j < 8; j++) ha[j] = *(const short8*)(asrc + (j << 5));
    f32x4 a0 = {0.f, 0.f, 0.f, 0.f}, a1 = {0.f, 0.f, 0.f, 0.f};
#pragma unroll
    for (int blk = 0; blk < 4; blk++) {
#pragma unroll
      for (int j = 0; j < 8; j++) {
        int kk = (blk << 3) + j;
        a0 = __builtin_amdgcn_mfma_f32_16x16x32_bf16(ha[j], bbase0[kk << 7], a0, 0, 0, 0);
        a1 = __builtin_amdgcn_mfma_f32_16x16x32_bf16(ha[j], bbase1[kk << 7], a1, 0, 0, 0);
        if (blk < 3) ha[j] = *(const short8*)(asrc + ((kk + 8) << 5));
      }
    }
    pbuf[0][mt][0][lane] = a0;
    pbuf[0][mt][1][lane] = a1;
  }
  __syncthreads();   // partial[0] sealed

  for (int s = 0; s < TT; s++) {
    if (isA) {
      // ---- aggregator roles (one wave per layer on the whole GPU) ----
      if (bid == 0 && w == 0 && s >= 1) {
        int* base = cnt0 + ((s - 1) << 9) + ((lane & 7) << 6);
        for (;;) {
          int v = GLD(base);
#pragma unroll
          for (int m2 = 1; m2 < 64; m2 <<= 1) v += __shfl_xor(v, m2, 64);
          if (v >= 1024) break;   // 8 dup loads per sub-line x 128
        }
#pragma unroll
        for (int k2 = 0; k2 < 4; k2++) GST(go0 + ((lane | (k2 << 6)) << 5), s);
      } else if (bid == 128 && w == 0 && s >= 1) {
        int* base = cnt1 + ((s - 1) << 9) + ((lane & 7) << 6);
        for (;;) {
          int v = GLD(base);
#pragma unroll
          for (int m2 = 1; m2 < 64; m2 <<= 1) v += __shfl_xor(v, m2, 64);
          if (v >= 1024) break;
        }
#pragma unroll
        for (int k2 = 0; k2 < 2; k2++) GST(go1 + ((lane | (k2 << 6)) << 5), s);
      }
      // ---- A-compute for step s+1 into pbuf[(s+1)&1] ----
      if (s + 1 < TT) {
        if (layer == 1) { while (GLD(go0 + ((128 + g) << 5)) < s + 2) {} }
        const unsigned short* asrc = ((layer == 0) ? xbf + (size_t)(s + 1) * BH
                                                   : h0hist + (size_t)(s + 2) * BH) + rowoff;
        short8 ha[8];
#pragma unroll
        for (int j = 0; j < 8; j++) ha[j] = *(const short8*)(asrc + (j << 5));
        f32x4 a0 = {0.f, 0.f, 0.f, 0.f}, a1 = {0.f, 0.f, 0.f, 0.f};
#pragma unroll
        for (int blk = 0; blk < 4; blk++) {
#pragma unroll
          for (int j = 0; j < 8; j++) {
            int kk = (blk << 3) + j;
            a0 = __builtin_amdgcn_mfma_f32_16x16x32_bf16(ha[j], bbase0[kk << 7], a0, 0, 0, 0);
            a1 = __builtin_amdgcn_mfma_f32_16x16x32_bf16(ha[j], bbase1[kk << 7], a1, 0, 0, 0);
            if (blk < 3) ha[j] = *(const short8*)(asrc + ((kk + 8) << 5));
          }
        }
        int buf = (s + 1) & 1;
        pbuf[buf][mt][0][lane] = a0;
        pbuf[buf][mt][1][lane] = a1;
      }
    } else {
      // ---- B tight wait: all lanes of all 4 B-waves poll the private mailbox ----
      if (s >= 1) {
        int* mb = ((layer == 0) ? go0 : go1) + (g << 5);
        while (GLD(mb) < s) {}
      }
      // ---- recurrent GEMM: h[s] x second K-half, seeded from partial ----
      const unsigned short* inB = myhist + (size_t)s * BH + rowoff;
      short8 ha[8];
#pragma unroll
      for (int j = 0; j < 8; j++) ha[j] = *(const short8*)(inB + (j << 5));
      f32x4 acc0 = pbuf[s & 1][mt][0][lane];
      f32x4 acc1 = pbuf[s & 1][mt][1][lane];
#pragma unroll
      for (int blk = 0; blk < 4; blk++) {
#pragma unroll
        for (int j = 0; j < 8; j++) {
          int kk = (blk << 3) + j;
          acc0 = __builtin_amdgcn_mfma_f32_16x16x32_bf16(ha[j], bbase0[(32 + kk) << 7], acc0, 0, 0, 0);
          acc1 = __builtin_amdgcn_mfma_f32_16x16x32_bf16(ha[j], bbase1[(32 + kk) << 7], acc1, 0, 0, 0);
          if (blk < 3) ha[j] = *(const short8*)(inB + ((kk + 8) << 5));
        }
      }

      // ---- epilogue: activation, gather, state update, stores (both n-tiles) ----
      unsigned int* hb32 = (unsigned int*)(myhist + (size_t)(s + 1) * BH);
      float* hf = (layer == 1) ? out + (size_t)s * BH
                               : ((s == TT - 1) ? out + (size_t)TT * BH : nullptr);
      const int srcl = (lane & 48) | jl;
#pragma unroll
      for (int nt2 = 0; nt2 < 2; nt2++) {
        f32x4 acc = nt2 ? acc1 : acc0;
        const int jg = jgb + (nt2 << 2);
        const float blane = nt2 ? blane1 : blane0;
#pragma unroll
        for (int r = 0; r < 4; r++) {
          float a = acc[r] + blane;
          float t = (q == 2) ? (a + a) : -a;
          float e = __expf(t);
          float act = (q == 2) ? (1.0f - 2.0f / (e + 1.0f)) : (1.0f / (1.0f + e));
          float vi = __shfl(act, srcl,      64);
          float vf = __shfl(act, srcl | 4,  64);
          float vg = __shfl(act, srcl | 8,  64);
          float vo = __shfl(act, srcl | 12, 64);
          float hn = 0.f;
          int m = m0 + (hi << 2) + r;
          int idx = (m << 10) + jg;
          if (n < 4) {
            float cn = vi * vg + vf * creg[nt2][r];
            hn = vo * ftanhf(cn);
            creg[nt2][r] = cn;
            if (s == TT - 1) {
              if (layer == 1) {
                out[(size_t)TT * BH + BH + idx] = hn;        // final h, layer 1
                out[(size_t)TT * BH + 3 * BH + idx] = cn;    // final c, layer 1
              } else {
                out[(size_t)TT * BH + 2 * BH + idx] = cn;    // final c, layer 0
              }
            }
          }
          float hn2 = __shfl(hn, lane + 1, 64);
          if (n < 4 && (n & 1) == 0) {
            unsigned int pack = (unsigned int)f2bf(hn) | ((unsigned int)f2bf(hn2) << 16);
            GST(hb32 + (idx >> 1), pack);
            if (hf) *(float2*)(hf + idx) = make_float2(hn, hn2);
          }
        }
      }
    }

    // ---- end of step: seal pbuf[(s+1)&1], drain B stores, then publish ----
    __syncthreads();
    if (tid == 0) {
      int* c = (layer == 0) ? cnt0 : cnt1;
      atomicAdd(c + (s << 9) + ((g & 7) << 6), 1);
    }
  }

  // ---- agg0 post-loop: deliver go0 = TT for L1's final A-gates ----
  if (bid == 0 && w == 0) {
    int* base = cnt0 + ((TT - 1) << 9) + ((lane & 7) << 6);
    for (;;) {
      int v = GLD(base);
#pragma unroll
      for (int m2 = 1; m2 < 64; m2 <<= 1) v += __shfl_xor(v, m2, 64);
      if (v >= 1024) break;
    }
    GST(go0 + ((128 + lane) << 5), TT);
    GST(go0 + ((192 + lane) << 5), TT);
  }
}

extern "C" void kernel_launch(void* const* d_in, const int* in_sizes, int n_in,
                              void* d_out, int out_size, void* d_ws, size_t ws_size,
                              hipStream_t stream) {
  (void)in_sizes; (void)n_in; (void)out_size; (void)ws_size;
  const float* x    = (const float*)d_in[0];
  const float* h0in = (const float*)d_in[1];
  const float* c0in = (const float*)d_in[2];
  const float* W0   = (const float*)d_in[3];
  const float* b0   = (const float*)d_in[4];
  const float* W1   = (const float*)d_in[5];
  const float* b1   = (const float*)d_in[6];
  float* out = (float*)d_out;

  char* ws = (char*)d_ws;
  const size_t HIST = (size_t)(TT + 1) * BH * sizeof(unsigned short);  // 67,239,936 B
  unsigned short* Xbf    = (unsigned short*)(ws);                      // 64 MB
  unsigned short* W0s    = (unsigned short*)(ws + 67108864);           // 16 MB
  unsigned short* W1s    = (unsigned short*)(ws + 83886080);           // 16 MB
  unsigned short* h0hist = (unsigned short*)(ws + 100663296);          // 64.1 MB
  unsigned short* h1hist = (unsigned short*)(ws + 100663296 + HIST);   // 64.1 MB
  int* cnt               = (int*)(ws + 100663296 + 2 * HIST);          // cnt + mailboxes

  const size_t CNT_BYTES = ((size_t)(1048 << 9) + (256 << 5) + (128 << 5)) * sizeof(int);
  hipMemsetAsync(cnt, 0, CNT_BYTES, stream);
  cvt_x_kernel<<<2048, 256, 0, stream>>>(x, Xbf);
  cvt_w_kernel<<<4096, 256, 0, stream>>>(W0, W0s);
  cvt_w_kernel<<<4096, 256, 0, stream>>>(W1, W1s);
  init_state_kernel<<<256, 256, 0, stream>>>(h0in, h0hist, h1hist);

  lstm_persist<<<256, 512, 0, stream>>>(W0s, W1s, b0, b1, Xbf,
                                        h0hist, h1hist, c0in, out, cnt);
}